// Round 6
// baseline (280.701 us; speedup 1.0000x reference)
//
#include <hip/hip_runtime.h>

// ---------------------------------------------------------------------------
// GraphSAGE 2-layer, mean aggregation.
//   L1: h = relu( mean_nbr(x) @ W_l1 + x @ W_r1 + b1 )   (IN=2 -> aggregate x first)
//   L2: out = mean_nbr(h) @ W_l2 + h @ W_r2 + b2
// R2: CSR via 2-level MSD binning (bucket = dst>>7).
// R3: k_gemm B staged in LDS (was latency-bound on serialized global B loads).
// R4: k_agg2 gathers h in fp8 e4m3 (HW cvt_pk_f32_fp8); ebuf packed to 1 uint.
// R5: k_agg2 was latency-bound on the csr->h8 dependent chain per iteration
//     (FETCH halving in R4 gave only -6us). Now: node's csr prefetched in ONE
//     vector load, indices distributed via shfl (register-only), 8 gather
//     iterations wave-uniformly guarded and mutually independent -> up to 8
//     h8 gathers in flight per wave.
// ---------------------------------------------------------------------------

using f32x4 = __attribute__((ext_vector_type(4))) float;
using f32x2 = __attribute__((ext_vector_type(2))) float;
using s16x8 = __attribute__((ext_vector_type(8))) short;

__device__ __forceinline__ unsigned short f32_to_bf16(float f) {
  unsigned int u = __float_as_uint(f);
  u += 0x7fffu + ((u >> 16) & 1u);          // round-to-nearest-even
  return (unsigned short)(u >> 16);
}

#define EDGE_TILE 4096

// ---- bin pass 1: bucket histogram (LDS-local, one global atomic/bucket) ----
__global__ __launch_bounds__(256) void k_bhist(const int* __restrict__ ei, int* __restrict__ bcnt,
                                               int E, int nb) {
  __shared__ int h[1024];
  int t = threadIdx.x;
  for (int i = t; i < nb; i += 256) h[i] = 0;
  __syncthreads();
  int tbeg = blockIdx.x * EDGE_TILE;
  int tend = min(tbeg + EDGE_TILE, E);
  const int* dstp = ei + E;
  for (int i = tbeg + t; i < tend; i += 256) atomicAdd(&h[dstp[i] >> 7], 1);
  __syncthreads();
  for (int i = t; i < nb; i += 256) if (h[i]) atomicAdd(&bcnt[i], h[i]);
}

// ---- bin pass 2: scan bucket counts -> bases + cursor copy ------------------
__global__ __launch_bounds__(1024) void k_bscan(const int* __restrict__ bcnt, int* __restrict__ bbase,
                                                int* __restrict__ bcur, int nb, int E) {
  __shared__ int sm[2][1024];
  int t = threadIdx.x;
  int v0 = (t < nb) ? bcnt[t] : 0;
  sm[0][t] = v0;
  __syncthreads();
  int src = 0;
  for (int st = 1; st < 1024; st <<= 1) {
    int v = sm[src][t];
    if (t >= st) v += sm[src][t - st];
    sm[src ^ 1][t] = v; __syncthreads(); src ^= 1;
  }
  int ex = sm[src][t] - v0;
  if (t < nb) { bbase[t] = ex; bcur[t] = ex; }
  if (t == 0) bbase[nb] = E;
}

// ---- bin pass 3: scatter packed (src<<7 | dst&127) into bucket-grouped ebuf -
__global__ __launch_bounds__(256) void k_bscatter(const int* __restrict__ ei, int* __restrict__ bcur,
                                                  unsigned int* __restrict__ ebuf, int E, int nb) {
  __shared__ int h[1024];
  __shared__ int base[1024];
  int t = threadIdx.x;
  for (int i = t; i < nb; i += 256) h[i] = 0;
  __syncthreads();
  int tbeg = blockIdx.x * EDGE_TILE;
  int tend = min(tbeg + EDGE_TILE, E);
  const int* srcp = ei;
  const int* dstp = ei + E;
  for (int i = tbeg + t; i < tend; i += 256) atomicAdd(&h[dstp[i] >> 7], 1);
  __syncthreads();
  for (int i = t; i < nb; i += 256) {
    int c = h[i];
    base[i] = c ? atomicAdd(&bcur[i], c) : 0;
    h[i] = 0;                                   // reuse as rank cursor
  }
  __syncthreads();
  for (int i = tbeg + t; i < tend; i += 256) {
    int d = dstp[i];
    int b = d >> 7;
    int r = atomicAdd(&h[b], 1);
    ebuf[base[b] + r] = ((unsigned)srcp[i] << 7) | (unsigned)(d & 127);
  }
}

// ---- bin pass 4: per-bucket local CSR build (offs + csr), block per bucket --
__global__ __launch_bounds__(256) void k_bucket_csr(const unsigned int* __restrict__ ebuf,
                                                    const int* __restrict__ bbase,
                                                    int* __restrict__ offs, int* __restrict__ csr,
                                                    int N, int nb) {
  __shared__ int deg[128];
  __shared__ int loff[128];
  __shared__ int cur[128];
  int b = blockIdx.x;
  int t = threadIdx.x;
  int lo = bbase[b], hi = bbase[b + 1];
  if (t < 128) deg[t] = 0;
  __syncthreads();
  for (int i = lo + t; i < hi; i += 256) atomicAdd(&deg[ebuf[i] & 127], 1);
  __syncthreads();
  if (t < 128) loff[t] = deg[t];
  __syncthreads();
  for (int st = 1; st < 128; st <<= 1) {
    int v = 0;
    if (t < 128 && t >= st) v = loff[t - st];
    __syncthreads();
    if (t < 128) loff[t] += v;
    __syncthreads();
  }
  if (t < 128) {
    int ex = loff[t] - deg[t];                 // exclusive prefix
    cur[t] = ex;
    int node = b * 128 + t;
    if (node < N) offs[node] = lo + ex;
  }
  if (b == nb - 1 && t == 0) offs[N] = hi;
  __syncthreads();
  for (int i = lo + t; i < hi; i += 256) {
    unsigned int e = ebuf[i];
    int r = atomicAdd(&cur[e & 127], 1);
    csr[lo + r] = (int)(e >> 7);
  }
}

// ---- layer-1 aggregation of x (2 dims), thread per node ---------------------
__global__ __launch_bounds__(256) void k_agg1(const int* __restrict__ offs, const int* __restrict__ csr,
                                              const float* __restrict__ x, float* __restrict__ agg1, int n) {
  int node = blockIdx.x * 256 + threadIdx.x;
  if (node >= n) return;
  int beg = offs[node], end = offs[node + 1];
  float s0 = 0.f, s1 = 0.f;
  const float2* x2 = (const float2*)x;
  for (int e = beg; e < end; ++e) {
    int s = csr[e];
    float2 v = x2[s];
    s0 += v.x; s1 += v.y;
  }
  agg1[2 * node] = s0; agg1[2 * node + 1] = s1;
}

// ---- layer-1 dense: h = relu(...), bf16 + fp8 out; 2 cols/thread ------------
__global__ __launch_bounds__(256) void k_layer1(const float* __restrict__ x, const float* __restrict__ agg1,
                                                const int* __restrict__ offs,
                                                const float* __restrict__ Wl, const float* __restrict__ Wr,
                                                const float* __restrict__ b1,
                                                unsigned int* __restrict__ h16,
                                                unsigned short* __restrict__ h8, int n) {
  int gid = blockIdx.x * 256 + threadIdx.x;
  int node = gid >> 6;
  if (node >= n) return;
  int c = (gid & 63) * 2;
  int deg = offs[node + 1] - offs[node];
  float sc = 1.0f / (float)max(deg, 1);
  float a0 = agg1[2 * node] * sc, a1 = agg1[2 * node + 1] * sc;
  float x0 = x[2 * node], x1 = x[2 * node + 1];
  float r0 = fmaf(a0, Wl[c],     fmaf(a1, Wl[128 + c],     fmaf(x0, Wr[c],     fmaf(x1, Wr[128 + c],     b1[c]))));
  float r1 = fmaf(a0, Wl[c + 1], fmaf(a1, Wl[128 + c + 1], fmaf(x0, Wr[c + 1], fmaf(x1, Wr[128 + c + 1], b1[c + 1]))));
  r0 = r0 > 0.f ? r0 : 0.f;
  r1 = r1 > 0.f ? r1 : 0.f;
  unsigned int packed = (unsigned int)f32_to_bf16(r0) | ((unsigned int)f32_to_bf16(r1) << 16);
  h16[(size_t)node * 64 + (gid & 63)] = packed;
  unsigned int p8 = (unsigned int)__builtin_amdgcn_cvt_pk_fp8_f32(r0, r1, 0, false);
  h8[(size_t)node * 64 + (gid & 63)] = (unsigned short)(p8 & 0xffffu);
}

// ---- prep: Wt[col][k] bf16, k<128 from W_l2, k>=128 from W_r2 ---------------
__global__ __launch_bounds__(256) void k_prepw(const float* __restrict__ Wl2, const float* __restrict__ Wr2,
                                               unsigned short* __restrict__ wt) {
  int tid = blockIdx.x * 256 + threadIdx.x;   // tid = c*256 + k
  if (tid >= 128 * 256) return;
  int c = tid >> 8, k = tid & 255;
  float v = (k < 128) ? Wl2[k * 128 + c] : Wr2[(k - 128) * 128 + c];
  wt[tid] = f32_to_bf16(v);
}

// ---- layer-2 aggregation: wave/node; csr prefetched in 1 vector load, up to
//      8 independent fp8 row gathers in flight (wave-uniform iter guards) -----
__global__ __launch_bounds__(256) void k_agg2(const int* __restrict__ offs, const int* __restrict__ csr,
                                              const unsigned char* __restrict__ h8,
                                              unsigned int* __restrict__ a16, int n) {
  int node = blockIdx.x * 4 + (threadIdx.x >> 6);
  if (node >= n) return;
  int lane = threadIdx.x & 63;
  int g  = lane >> 3;        // edge subgroup 0..7
  int cb = lane & 7;         // col block: cols cb*16 .. cb*16+15
  int beg = offs[node], end = offs[node + 1];
  int deg = end - beg;

  float acc[16];
#pragma unroll
  for (int j = 0; j < 16; ++j) acc[j] = 0.f;

  for (int c = 0; c < deg; c += 64) {
    int rem = min(deg - c, 64);                      // >0
    // one vector load covers this chunk's indices (dup-clamped for tail lanes)
    int e_l = csr[beg + c + min(lane, rem - 1)];
#pragma unroll
    for (int i = 0; i < 8; ++i) {
      if (i * 8 < rem) {                             // wave-uniform guard
        int idx = i * 8 + g;
        float w = idx < rem ? 1.f : 0.f;
        int s = __shfl(e_l, min(idx, rem - 1), 64);  // register-only distribute
        uint4 v = *(const uint4*)(h8 + (size_t)s * 128 + cb * 16);
        f32x2 p;
        p = __builtin_amdgcn_cvt_pk_f32_fp8((int)v.x, false); acc[0]  = fmaf(w, p[0], acc[0]);  acc[1]  = fmaf(w, p[1], acc[1]);
        p = __builtin_amdgcn_cvt_pk_f32_fp8((int)v.x, true);  acc[2]  = fmaf(w, p[0], acc[2]);  acc[3]  = fmaf(w, p[1], acc[3]);
        p = __builtin_amdgcn_cvt_pk_f32_fp8((int)v.y, false); acc[4]  = fmaf(w, p[0], acc[4]);  acc[5]  = fmaf(w, p[1], acc[5]);
        p = __builtin_amdgcn_cvt_pk_f32_fp8((int)v.y, true);  acc[6]  = fmaf(w, p[0], acc[6]);  acc[7]  = fmaf(w, p[1], acc[7]);
        p = __builtin_amdgcn_cvt_pk_f32_fp8((int)v.z, false); acc[8]  = fmaf(w, p[0], acc[8]);  acc[9]  = fmaf(w, p[1], acc[9]);
        p = __builtin_amdgcn_cvt_pk_f32_fp8((int)v.z, true);  acc[10] = fmaf(w, p[0], acc[10]); acc[11] = fmaf(w, p[1], acc[11]);
        p = __builtin_amdgcn_cvt_pk_f32_fp8((int)v.w, false); acc[12] = fmaf(w, p[0], acc[12]); acc[13] = fmaf(w, p[1], acc[13]);
        p = __builtin_amdgcn_cvt_pk_f32_fp8((int)v.w, true);  acc[14] = fmaf(w, p[0], acc[14]); acc[15] = fmaf(w, p[1], acc[15]);
      }
    }
  }

#pragma unroll
  for (int j = 0; j < 16; ++j) {
    acc[j] += __shfl_xor(acc[j], 8, 64);
    acc[j] += __shfl_xor(acc[j], 16, 64);
    acc[j] += __shfl_xor(acc[j], 32, 64);
  }
  if (g == 0) {            // lanes 0..7, cb = lane
    float scale = 1.0f / (float)max(deg, 1);
    unsigned int u[8];
#pragma unroll
    for (int k = 0; k < 8; ++k)
      u[k] = (unsigned int)f32_to_bf16(acc[2 * k] * scale) |
             ((unsigned int)f32_to_bf16(acc[2 * k + 1] * scale) << 16);
    unsigned int* dst = a16 + (size_t)node * 64 + cb * 8;   // row = 64 uints
    *(uint4*)dst       = make_uint4(u[0], u[1], u[2], u[3]);
    *(uint4*)(dst + 4) = make_uint4(u[4], u[5], u[6], u[7]);
  }
}

// ---- layer-2 GEMM: out[N,128] = [agg2|h](bf16) @ Wt(bf16) + b2, MFMA --------
// Block: one column-half (64 cols) staged in LDS (row stride 264 shorts);
// 4 waves x one 16-row tile each.
__global__ __launch_bounds__(256) void k_gemm(const unsigned short* __restrict__ a16,
                                              const unsigned short* __restrict__ h16,
                                              const unsigned short* __restrict__ wt,
                                              const float* __restrict__ b2,
                                              float* __restrict__ out, int nrows) {
  __shared__ unsigned short bs[64 * 264];   // 33792 B
  int half = blockIdx.x & 1;
  int tg   = blockIdx.x >> 1;

#pragma unroll
  for (int i = 0; i < 8; ++i) {
    int c = threadIdx.x + i * 256;          // 0..2047
    int row = c >> 5, off = c & 31;         // off in 16B units
    *(uint4*)(bs + row * 264 + off * 8) =
        *(const uint4*)(wt + ((size_t)(half * 64 + row)) * 256 + off * 8);
  }
  __syncthreads();

  int wv   = threadIdx.x >> 6;
  int lane = threadIdx.x & 63;
  int m16 = lane & 15, quad = lane >> 4;
  int tile = tg * 4 + wv;
  if (tile * 16 >= nrows) return;

  int r  = tile * 16 + m16;
  int rc = r < nrows ? r : nrows - 1;
  const unsigned short* arow = a16 + (size_t)rc * 128 + quad * 8;
  const unsigned short* hrow = h16 + (size_t)rc * 128 + quad * 8;

  s16x8 afrag[8];
#pragma unroll
  for (int c4 = 0; c4 < 4; ++c4) {
    afrag[c4]     = *(const s16x8*)(arow + c4 * 32);   // A[m][k], k-chunk c4
    afrag[4 + c4] = *(const s16x8*)(hrow + c4 * 32);
  }

  f32x4 acc[4];
#pragma unroll
  for (int t = 0; t < 4; ++t) acc[t] = (f32x4){0.f, 0.f, 0.f, 0.f};

  const unsigned short* bbase = bs + m16 * 264 + quad * 8;
#pragma unroll
  for (int ch = 0; ch < 8; ++ch) {
#pragma unroll
    for (int t = 0; t < 4; ++t) {
      s16x8 bf = *(const s16x8*)(bbase + t * 16 * 264 + ch * 32); // B[k][n]
      acc[t] = __builtin_amdgcn_mfma_f32_16x16x32_bf16(afrag[ch], bf, acc[t], 0, 0, 0);
    }
  }

#pragma unroll
  for (int t = 0; t < 4; ++t) {
    int col = half * 64 + t * 16 + m16;
    float bias = b2[col];
#pragma unroll
    for (int i = 0; i < 4; ++i) {
      int row = tile * 16 + quad * 4 + i;   // C/D: col=lane&15, row=quad*4+reg
      if (row < nrows) out[(size_t)row * 128 + col] = acc[t][i] + bias;
    }
  }
}

// ---------------------------------------------------------------------------
extern "C" void kernel_launch(void* const* d_in, const int* in_sizes, int n_in,
                              void* d_out, int out_size, void* d_ws, size_t ws_size,
                              hipStream_t stream) {
  const float* x    = (const float*)d_in[0];
  const int*   ei   = (const int*)d_in[1];
  const float* Wl1  = (const float*)d_in[2];
  const float* Wr1  = (const float*)d_in[3];
  const float* b1   = (const float*)d_in[4];
  const float* Wl2  = (const float*)d_in[5];
  const float* Wr2  = (const float*)d_in[6];
  const float* b2   = (const float*)d_in[7];
  float* out = (float*)d_out;

  const int N = in_sizes[0] / 2;     // 100000
  const int E = in_sizes[1] / 2;     // 1600000
  const int nb = (N + 127) >> 7;     // 782 buckets

  // workspace carve-up (256B aligned)
  char* p = (char*)d_ws;
  auto take = [&](size_t bytes) { char* r = p; p += (bytes + 255) & ~(size_t)255; return r; };
  int* bcnt            = (int*)take(1024 * 4);
  int* bbase           = (int*)take(1025 * 4);
  int* bcur            = (int*)take(1024 * 4);
  int* offs            = (int*)take((size_t)(N + 1) * 4);
  int* csr             = (int*)take((size_t)E * 4);
  unsigned int* ebuf   = (unsigned int*)take((size_t)E * 4);
  float* agg1          = (float*)take((size_t)N * 2 * 4);
  unsigned short* h16  = (unsigned short*)take((size_t)N * 128 * 2);
  unsigned short* a16  = (unsigned short*)take((size_t)N * 128 * 2);
  unsigned short* h8   = (unsigned short*)take((size_t)N * 128);
  unsigned short* wt   = (unsigned short*)take((size_t)128 * 256 * 2);

  const int nblk_e = (E + EDGE_TILE - 1) / EDGE_TILE;   // 391
  const int ntiles = (N + 15) / 16;                      // 6250

  hipMemsetAsync(bcnt, 0, 1024 * 4, stream);

  k_bhist     <<<nblk_e, 256, 0, stream>>>(ei, bcnt, E, nb);
  k_bscan     <<<1, 1024, 0, stream>>>(bcnt, bbase, bcur, nb, E);
  k_bscatter  <<<nblk_e, 256, 0, stream>>>(ei, bcur, ebuf, E, nb);
  k_bucket_csr<<<nb, 256, 0, stream>>>(ebuf, bbase, offs, csr, N, nb);
  k_agg1      <<<(N + 255) / 256, 256, 0, stream>>>(offs, csr, x, agg1, N);
  k_layer1    <<<((size_t)N * 64 + 255) / 256, 256, 0, stream>>>(x, agg1, offs, Wl1, Wr1, b1,
                                                                 (unsigned int*)h16, h8, N);
  k_prepw     <<<(128 * 256) / 256, 256, 0, stream>>>(Wl2, Wr2, wt);
  k_agg2      <<<(N + 3) / 4, 256, 0, stream>>>(offs, csr, (const unsigned char*)h8,
                                                (unsigned int*)a16, N);
  k_gemm      <<<((ntiles + 3) / 4) * 2, 256, 0, stream>>>(a16, h16, wt, b2, out, N);
}

// Round 7
// 252.699 us; speedup vs baseline: 1.1108x; 1.1108x over previous
//
#include <hip/hip_runtime.h>

// ---------------------------------------------------------------------------
// GraphSAGE 2-layer, mean aggregation.
//   L1: h = relu( mean_nbr(x) @ W_l1 + x @ W_r1 + b1 )   (IN=2 -> aggregate x first)
//   L2: out = mean_nbr(h) @ W_l2 + h @ W_r2 + b2
// R2: CSR via 2-level MSD binning (bucket = dst>>7).
// R3: k_gemm B staged in LDS.
// R4: k_agg2 gathers h in fp8 e4m3; ebuf packed to 1 uint.
// R5: FAILED (shfl distribute) -> kernel is VALU-issue heavy, not mem-latency.
// R6: k_agg2 restructured: 8 nodes/wave, 8 lanes/node, lane owns 16 cols of
//     all its node's edges -> NO cross-lane reduction tail (was ~50% of VALU).
//     k_agg1 folded into k_bucket_csr (x-sum via LDS float atomics).
// ---------------------------------------------------------------------------

using f32x4 = __attribute__((ext_vector_type(4))) float;
using f32x2 = __attribute__((ext_vector_type(2))) float;
using s16x8 = __attribute__((ext_vector_type(8))) short;

__device__ __forceinline__ unsigned short f32_to_bf16(float f) {
  unsigned int u = __float_as_uint(f);
  u += 0x7fffu + ((u >> 16) & 1u);          // round-to-nearest-even
  return (unsigned short)(u >> 16);
}

#define EDGE_TILE 4096

// ---- bin pass 1: bucket histogram (LDS-local, one global atomic/bucket) ----
__global__ __launch_bounds__(256) void k_bhist(const int* __restrict__ ei, int* __restrict__ bcnt,
                                               int E, int nb) {
  __shared__ int h[1024];
  int t = threadIdx.x;
  for (int i = t; i < nb; i += 256) h[i] = 0;
  __syncthreads();
  int tbeg = blockIdx.x * EDGE_TILE;
  int tend = min(tbeg + EDGE_TILE, E);
  const int* dstp = ei + E;
  for (int i = tbeg + t; i < tend; i += 256) atomicAdd(&h[dstp[i] >> 7], 1);
  __syncthreads();
  for (int i = t; i < nb; i += 256) if (h[i]) atomicAdd(&bcnt[i], h[i]);
}

// ---- bin pass 2: scan bucket counts -> bases + cursor copy ------------------
__global__ __launch_bounds__(1024) void k_bscan(const int* __restrict__ bcnt, int* __restrict__ bbase,
                                                int* __restrict__ bcur, int nb, int E) {
  __shared__ int sm[2][1024];
  int t = threadIdx.x;
  int v0 = (t < nb) ? bcnt[t] : 0;
  sm[0][t] = v0;
  __syncthreads();
  int src = 0;
  for (int st = 1; st < 1024; st <<= 1) {
    int v = sm[src][t];
    if (t >= st) v += sm[src][t - st];
    sm[src ^ 1][t] = v; __syncthreads(); src ^= 1;
  }
  int ex = sm[src][t] - v0;
  if (t < nb) { bbase[t] = ex; bcur[t] = ex; }
  if (t == 0) bbase[nb] = E;
}

// ---- bin pass 3: scatter packed (src<<7 | dst&127) into bucket-grouped ebuf -
__global__ __launch_bounds__(256) void k_bscatter(const int* __restrict__ ei, int* __restrict__ bcur,
                                                  unsigned int* __restrict__ ebuf, int E, int nb) {
  __shared__ int h[1024];
  __shared__ int base[1024];
  int t = threadIdx.x;
  for (int i = t; i < nb; i += 256) h[i] = 0;
  __syncthreads();
  int tbeg = blockIdx.x * EDGE_TILE;
  int tend = min(tbeg + EDGE_TILE, E);
  const int* srcp = ei;
  const int* dstp = ei + E;
  for (int i = tbeg + t; i < tend; i += 256) atomicAdd(&h[dstp[i] >> 7], 1);
  __syncthreads();
  for (int i = t; i < nb; i += 256) {
    int c = h[i];
    base[i] = c ? atomicAdd(&bcur[i], c) : 0;
    h[i] = 0;                                   // reuse as rank cursor
  }
  __syncthreads();
  for (int i = tbeg + t; i < tend; i += 256) {
    int d = dstp[i];
    int b = d >> 7;
    int r = atomicAdd(&h[b], 1);
    ebuf[base[b] + r] = ((unsigned)srcp[i] << 7) | (unsigned)(d & 127);
  }
}

// ---- bin pass 4: per-bucket CSR build + layer-1 x aggregation ---------------
// One pass over the bucket's edges counts degrees AND accumulates x sums
// (LDS float atomics); second pass fills csr. (R6: absorbs old k_agg1.)
__global__ __launch_bounds__(256) void k_bucket_csr(const unsigned int* __restrict__ ebuf,
                                                    const int* __restrict__ bbase,
                                                    const float* __restrict__ x,
                                                    int* __restrict__ offs, int* __restrict__ csr,
                                                    float* __restrict__ agg1,
                                                    int N, int nb) {
  __shared__ int deg[128];
  __shared__ int loff[128];
  __shared__ int cur[128];
  __shared__ float sx0[128];
  __shared__ float sx1[128];
  int b = blockIdx.x;
  int t = threadIdx.x;
  int lo = bbase[b], hi = bbase[b + 1];
  if (t < 128) { deg[t] = 0; sx0[t] = 0.f; sx1[t] = 0.f; }
  __syncthreads();
  const float2* x2 = (const float2*)x;
  for (int i = lo + t; i < hi; i += 256) {
    unsigned int e = ebuf[i];
    int d = e & 127;
    float2 v = x2[e >> 7];
    atomicAdd(&deg[d], 1);
    atomicAdd(&sx0[d], v.x);
    atomicAdd(&sx1[d], v.y);
  }
  __syncthreads();
  if (t < 128) loff[t] = deg[t];
  __syncthreads();
  for (int st = 1; st < 128; st <<= 1) {
    int v = 0;
    if (t < 128 && t >= st) v = loff[t - st];
    __syncthreads();
    if (t < 128) loff[t] += v;
    __syncthreads();
  }
  if (t < 128) {
    int ex = loff[t] - deg[t];                 // exclusive prefix
    cur[t] = ex;
    int node = b * 128 + t;
    if (node < N) {
      offs[node] = lo + ex;
      agg1[2 * node]     = sx0[t];
      agg1[2 * node + 1] = sx1[t];
    }
  }
  if (b == nb - 1 && t == 0) offs[N] = hi;
  __syncthreads();
  for (int i = lo + t; i < hi; i += 256) {
    unsigned int e = ebuf[i];
    int r = atomicAdd(&cur[e & 127], 1);
    csr[lo + r] = (int)(e >> 7);
  }
}

// ---- layer-1 dense: h = relu(...), bf16 + fp8 out; 2 cols/thread ------------
__global__ __launch_bounds__(256) void k_layer1(const float* __restrict__ x, const float* __restrict__ agg1,
                                                const int* __restrict__ offs,
                                                const float* __restrict__ Wl, const float* __restrict__ Wr,
                                                const float* __restrict__ b1,
                                                unsigned int* __restrict__ h16,
                                                unsigned short* __restrict__ h8, int n) {
  int gid = blockIdx.x * 256 + threadIdx.x;
  int node = gid >> 6;
  if (node >= n) return;
  int c = (gid & 63) * 2;
  int deg = offs[node + 1] - offs[node];
  float sc = 1.0f / (float)max(deg, 1);
  float a0 = agg1[2 * node] * sc, a1 = agg1[2 * node + 1] * sc;
  float x0 = x[2 * node], x1 = x[2 * node + 1];
  float r0 = fmaf(a0, Wl[c],     fmaf(a1, Wl[128 + c],     fmaf(x0, Wr[c],     fmaf(x1, Wr[128 + c],     b1[c]))));
  float r1 = fmaf(a0, Wl[c + 1], fmaf(a1, Wl[128 + c + 1], fmaf(x0, Wr[c + 1], fmaf(x1, Wr[128 + c + 1], b1[c + 1]))));
  r0 = r0 > 0.f ? r0 : 0.f;
  r1 = r1 > 0.f ? r1 : 0.f;
  unsigned int packed = (unsigned int)f32_to_bf16(r0) | ((unsigned int)f32_to_bf16(r1) << 16);
  h16[(size_t)node * 64 + (gid & 63)] = packed;
  unsigned int p8 = (unsigned int)__builtin_amdgcn_cvt_pk_fp8_f32(r0, r1, 0, false);
  h8[(size_t)node * 64 + (gid & 63)] = (unsigned short)(p8 & 0xffffu);
}

// ---- prep: Wt[col][k] bf16, k<128 from W_l2, k>=128 from W_r2 ---------------
__global__ __launch_bounds__(256) void k_prepw(const float* __restrict__ Wl2, const float* __restrict__ Wr2,
                                               unsigned short* __restrict__ wt) {
  int tid = blockIdx.x * 256 + threadIdx.x;   // tid = c*256 + k
  if (tid >= 128 * 256) return;
  int c = tid >> 8, k = tid & 255;
  float v = (k < 128) ? Wl2[k * 128 + c] : Wr2[(k - 128) * 128 + c];
  wt[tid] = f32_to_bf16(v);
}

// ---- layer-2 aggregation: 8 nodes/wave, 8 lanes/node, 16 cols/lane ----------
// No cross-lane reduction: each lane accumulates its 16 columns over all of
// its node's edges, then packs+stores directly. Unroll x2 -> 2 gathers/lane
// in flight; one edge row (128B fp8) = the node's 8 lanes x 16B.
#define ACC8(v)                                                                              \
  do {                                                                                       \
    f32x2 p;                                                                                 \
    p = __builtin_amdgcn_cvt_pk_f32_fp8((int)(v).x, false); acc[0] += p[0];  acc[1] += p[1]; \
    p = __builtin_amdgcn_cvt_pk_f32_fp8((int)(v).x, true);  acc[2] += p[0];  acc[3] += p[1]; \
    p = __builtin_amdgcn_cvt_pk_f32_fp8((int)(v).y, false); acc[4] += p[0];  acc[5] += p[1]; \
    p = __builtin_amdgcn_cvt_pk_f32_fp8((int)(v).y, true);  acc[6] += p[0];  acc[7] += p[1]; \
    p = __builtin_amdgcn_cvt_pk_f32_fp8((int)(v).z, false); acc[8] += p[0];  acc[9] += p[1]; \
    p = __builtin_amdgcn_cvt_pk_f32_fp8((int)(v).z, true);  acc[10] += p[0]; acc[11] += p[1];\
    p = __builtin_amdgcn_cvt_pk_f32_fp8((int)(v).w, false); acc[12] += p[0]; acc[13] += p[1];\
    p = __builtin_amdgcn_cvt_pk_f32_fp8((int)(v).w, true);  acc[14] += p[0]; acc[15] += p[1];\
  } while (0)

__global__ __launch_bounds__(256) void k_agg2(const int* __restrict__ offs, const int* __restrict__ csr,
                                              const unsigned char* __restrict__ h8,
                                              unsigned int* __restrict__ a16, int n) {
  int wv   = threadIdx.x >> 6;
  int lane = threadIdx.x & 63;
  int sub  = lane >> 3;          // node slot within wave: 0..7
  int cb   = lane & 7;           // 16-col block: cols cb*16 .. cb*16+15
  int node = blockIdx.x * 32 + wv * 8 + sub;
  if (node >= n) return;
  int beg = offs[node];
  int end = offs[node + 1];
  int deg = end - beg;
  const unsigned char* hb = h8 + cb * 16;

  float acc[16];
#pragma unroll
  for (int j = 0; j < 16; ++j) acc[j] = 0.f;

  int t = 0;
  for (; t + 1 < deg; t += 2) {
    int s0 = csr[beg + t];
    int s1 = csr[beg + t + 1];
    uint4 v0 = *(const uint4*)(hb + (size_t)s0 * 128);
    uint4 v1 = *(const uint4*)(hb + (size_t)s1 * 128);
    ACC8(v0);
    ACC8(v1);
  }
  if (t < deg) {
    int s0 = csr[beg + t];
    uint4 v0 = *(const uint4*)(hb + (size_t)s0 * 128);
    ACC8(v0);
  }

  float scale = 1.0f / (float)max(deg, 1);
  unsigned int u[8];
#pragma unroll
  for (int k = 0; k < 8; ++k)
    u[k] = (unsigned int)f32_to_bf16(acc[2 * k] * scale) |
           ((unsigned int)f32_to_bf16(acc[2 * k + 1] * scale) << 16);
  unsigned int* dst = a16 + (size_t)node * 64 + cb * 8;   // row = 64 uints
  *(uint4*)dst       = make_uint4(u[0], u[1], u[2], u[3]);
  *(uint4*)(dst + 4) = make_uint4(u[4], u[5], u[6], u[7]);
}

// ---- layer-2 GEMM: out[N,128] = [agg2|h](bf16) @ Wt(bf16) + b2, MFMA --------
// Block: one column-half (64 cols) staged in LDS (row stride 264 shorts);
// 4 waves x one 16-row tile each.
__global__ __launch_bounds__(256) void k_gemm(const unsigned short* __restrict__ a16,
                                              const unsigned short* __restrict__ h16,
                                              const unsigned short* __restrict__ wt,
                                              const float* __restrict__ b2,
                                              float* __restrict__ out, int nrows) {
  __shared__ unsigned short bs[64 * 264];   // 33792 B
  int half = blockIdx.x & 1;
  int tg   = blockIdx.x >> 1;

#pragma unroll
  for (int i = 0; i < 8; ++i) {
    int c = threadIdx.x + i * 256;          // 0..2047
    int row = c >> 5, off = c & 31;         // off in 16B units
    *(uint4*)(bs + row * 264 + off * 8) =
        *(const uint4*)(wt + ((size_t)(half * 64 + row)) * 256 + off * 8);
  }
  __syncthreads();

  int wv   = threadIdx.x >> 6;
  int lane = threadIdx.x & 63;
  int m16 = lane & 15, quad = lane >> 4;
  int tile = tg * 4 + wv;
  if (tile * 16 >= nrows) return;

  int r  = tile * 16 + m16;
  int rc = r < nrows ? r : nrows - 1;
  const unsigned short* arow = a16 + (size_t)rc * 128 + quad * 8;
  const unsigned short* hrow = h16 + (size_t)rc * 128 + quad * 8;

  s16x8 afrag[8];
#pragma unroll
  for (int c4 = 0; c4 < 4; ++c4) {
    afrag[c4]     = *(const s16x8*)(arow + c4 * 32);   // A[m][k], k-chunk c4
    afrag[4 + c4] = *(const s16x8*)(hrow + c4 * 32);
  }

  f32x4 acc[4];
#pragma unroll
  for (int t = 0; t < 4; ++t) acc[t] = (f32x4){0.f, 0.f, 0.f, 0.f};

  const unsigned short* bbase = bs + m16 * 264 + quad * 8;
#pragma unroll
  for (int ch = 0; ch < 8; ++ch) {
#pragma unroll
    for (int t = 0; t < 4; ++t) {
      s16x8 bf = *(const s16x8*)(bbase + t * 16 * 264 + ch * 32); // B[k][n]
      acc[t] = __builtin_amdgcn_mfma_f32_16x16x32_bf16(afrag[ch], bf, acc[t], 0, 0, 0);
    }
  }

#pragma unroll
  for (int t = 0; t < 4; ++t) {
    int col = half * 64 + t * 16 + m16;
    float bias = b2[col];
#pragma unroll
    for (int i = 0; i < 4; ++i) {
      int row = tile * 16 + quad * 4 + i;   // C/D: col=lane&15, row=quad*4+reg
      if (row < nrows) out[(size_t)row * 128 + col] = acc[t][i] + bias;
    }
  }
}

// ---------------------------------------------------------------------------
extern "C" void kernel_launch(void* const* d_in, const int* in_sizes, int n_in,
                              void* d_out, int out_size, void* d_ws, size_t ws_size,
                              hipStream_t stream) {
  const float* x    = (const float*)d_in[0];
  const int*   ei   = (const int*)d_in[1];
  const float* Wl1  = (const float*)d_in[2];
  const float* Wr1  = (const float*)d_in[3];
  const float* b1   = (const float*)d_in[4];
  const float* Wl2  = (const float*)d_in[5];
  const float* Wr2  = (const float*)d_in[6];
  const float* b2   = (const float*)d_in[7];
  float* out = (float*)d_out;

  const int N = in_sizes[0] / 2;     // 100000
  const int E = in_sizes[1] / 2;     // 1600000
  const int nb = (N + 127) >> 7;     // 782 buckets

  // workspace carve-up (256B aligned)
  char* p = (char*)d_ws;
  auto take = [&](size_t bytes) { char* r = p; p += (bytes + 255) & ~(size_t)255; return r; };
  int* bcnt            = (int*)take(1024 * 4);
  int* bbase           = (int*)take(1025 * 4);
  int* bcur            = (int*)take(1024 * 4);
  int* offs            = (int*)take((size_t)(N + 1) * 4);
  int* csr             = (int*)take((size_t)E * 4);
  unsigned int* ebuf   = (unsigned int*)take((size_t)E * 4);
  float* agg1          = (float*)take((size_t)N * 2 * 4);
  unsigned short* h16  = (unsigned short*)take((size_t)N * 128 * 2);
  unsigned short* a16  = (unsigned short*)take((size_t)N * 128 * 2);
  unsigned short* h8   = (unsigned short*)take((size_t)N * 128);
  unsigned short* wt   = (unsigned short*)take((size_t)128 * 256 * 2);

  const int nblk_e = (E + EDGE_TILE - 1) / EDGE_TILE;   // 391
  const int ntiles = (N + 15) / 16;                      // 6250

  hipMemsetAsync(bcnt, 0, 1024 * 4, stream);

  k_bhist     <<<nblk_e, 256, 0, stream>>>(ei, bcnt, E, nb);
  k_bscan     <<<1, 1024, 0, stream>>>(bcnt, bbase, bcur, nb, E);
  k_bscatter  <<<nblk_e, 256, 0, stream>>>(ei, bcur, ebuf, E, nb);
  k_bucket_csr<<<nb, 256, 0, stream>>>(ebuf, bbase, x, offs, csr, agg1, N, nb);
  k_layer1    <<<((size_t)N * 64 + 255) / 256, 256, 0, stream>>>(x, agg1, offs, Wl1, Wr1, b1,
                                                                 (unsigned int*)h16, h8, N);
  k_prepw     <<<(128 * 256) / 256, 256, 0, stream>>>(Wl2, Wr2, wt);
  k_agg2      <<<(N + 31) / 32, 256, 0, stream>>>(offs, csr, (const unsigned char*)h8,
                                                  (unsigned int*)a16, N);
  k_gemm      <<<((ntiles + 3) / 4) * 2, 256, 0, stream>>>(a16, h16, wt, b2, out, N);
}